// Round 1
// baseline (219.038 us; speedup 1.0000x reference)
//
#include <hip/hip_runtime.h>
#include <hip/hip_bf16.h>

#define NNODES 50000
#define NSAMP  25
#define FEAT   128

typedef __attribute__((ext_vector_type(4))) float  f32x4;
typedef __attribute__((ext_vector_type(8))) __bf16 bf16x8;

__device__ __forceinline__ bf16x8 cvt2(const f32x4 lo, const f32x4 hi) {
  bf16x8 r;
  r[0] = (__bf16)lo[0]; r[1] = (__bf16)lo[1];
  r[2] = (__bf16)lo[2]; r[3] = (__bf16)lo[3];
  r[4] = (__bf16)hi[0]; r[5] = (__bf16)hi[1];
  r[6] = (__bf16)hi[2]; r[7] = (__bf16)hi[3];
  return r;
}

// Wave-per-node mean-pool aggregator:
//   out[n,f] = (1/25) * sum_s relu( sum_d e[nbr[n,s], d] * W[f,d] + b[f] )
// A = gathered e rows (25 -> padded 32 rows, 2 M-tiles of 16), K = 128 (4 steps of 32),
// B = W^T fully register-resident (8 f-tiles x 4 K-steps x 4 VGPR = 128 VGPRs).
// No LDS, no barriers. mfma_f32_16x16x32_bf16; C/D: col=lane&15, row=(lane>>4)*4+reg.
__global__ __launch_bounds__(256, 2)
void meanpool_mfma_kernel(const int* __restrict__ nbr,
                          const float* __restrict__ emb,
                          const float* __restrict__ W,
                          const float* __restrict__ b,
                          float* __restrict__ out)
{
  const int lane = threadIdx.x & 63;
  const int waveInBlock = threadIdx.x >> 6;
  const int wavesPerBlock = blockDim.x >> 6;
  const int wid = blockIdx.x * wavesPerBlock + waveInBlock;
  const int nWaves = gridDim.x * wavesPerBlock;

  const int col  = lane & 15;   // f within f-tile (B/D col), s within M-tile (A row)
  const int quad = lane >> 4;   // 0..3: k-subblock for A/B, row-group for D
  const int coff = quad * 8;    // float offset within a K=32 chunk

  // ---- Preload B fragments: B[k][f] = W[f][k]; lane holds W[nt*16+col][kk*32+coff .. +7]
  bf16x8 Bf[8][4];
  float  bias[8];
  #pragma unroll
  for (int nt = 0; nt < 8; ++nt) {
    const float* wrow = W + (nt * 16 + col) * FEAT;
    bias[nt] = b[nt * 16 + col];
    #pragma unroll
    for (int kk = 0; kk < 4; ++kk) {
      f32x4 lo = *(const f32x4*)(wrow + kk * 32 + coff);
      f32x4 hi = *(const f32x4*)(wrow + kk * 32 + coff + 4);
      Bf[nt][kk] = cvt2(lo, hi);
    }
  }

  const float inv = 1.0f / (float)NSAMP;

  for (int n = wid; n < NNODES; n += nWaves) {
    const int* nb = nbr + n * NSAMP;
    // A-tile rows: M-tile 0 = s 0..15 (all valid), M-tile 1 = s 16..31 (valid < 25)
    const int s1 = 16 + col;
    const int i0 = nb[col];
    const int i1 = nb[s1 < NSAMP ? s1 : NSAMP - 1];  // clamp pad rows (masked later)
    const float* r0 = emb + (long long)i0 * FEAT;
    const float* r1 = emb + (long long)i1 * FEAT;

    // ---- Gather A fragments directly in MFMA layout: lane reads 8 floats of its row
    bf16x8 A0[4], A1[4];
    #pragma unroll
    for (int kk = 0; kk < 4; ++kk) {
      f32x4 lo0 = *(const f32x4*)(r0 + kk * 32 + coff);
      f32x4 hi0 = *(const f32x4*)(r0 + kk * 32 + coff + 4);
      f32x4 lo1 = *(const f32x4*)(r1 + kk * 32 + coff);
      f32x4 hi1 = *(const f32x4*)(r1 + kk * 32 + coff + 4);
      A0[kk] = cvt2(lo0, hi0);
      A1[kk] = cvt2(lo1, hi1);
    }

    float* orow = out + (long long)n * FEAT;

    #pragma unroll
    for (int nt = 0; nt < 8; ++nt) {
      f32x4 acc0 = {0.f, 0.f, 0.f, 0.f};
      f32x4 acc1 = {0.f, 0.f, 0.f, 0.f};
      #pragma unroll
      for (int kk = 0; kk < 4; ++kk) {
        acc0 = __builtin_amdgcn_mfma_f32_16x16x32_bf16(A0[kk], Bf[nt][kk], acc0, 0, 0, 0);
        acc1 = __builtin_amdgcn_mfma_f32_16x16x32_bf16(A1[kk], Bf[nt][kk], acc1, 0, 0, 0);
      }
      // Epilogue: bias + relu, mask pad rows (s >= 25), partial mean-pool in-lane
      float psum = 0.f;
      #pragma unroll
      for (int j = 0; j < 4; ++j) {
        // D row = quad*4 + j; tile0 rows 0..15 always valid
        psum += fmaxf(acc0[j] + bias[nt], 0.f);
        const int srow = 16 + quad * 4 + j;
        if (srow < NSAMP) psum += fmaxf(acc1[j] + bias[nt], 0.f);
      }
      // Reduce the 4 row-groups (lanes l, l^16, l^32, l^48 share the same col)
      psum += __shfl_xor(psum, 16);
      psum += __shfl_xor(psum, 32);
      if (lane < 16) orow[nt * 16 + lane] = psum * inv;
    }
  }
}

extern "C" void kernel_launch(void* const* d_in, const int* in_sizes, int n_in,
                              void* d_out, int out_size, void* d_ws, size_t ws_size,
                              hipStream_t stream) {
  const int*   nbr = (const int*)d_in[0];
  const float* emb = (const float*)d_in[1];
  const float* W   = (const float*)d_in[2];
  const float* b   = (const float*)d_in[3];
  float* out = (float*)d_out;

  dim3 grid(1024), block(256);
  hipLaunchKernelGGL(meanpool_mfma_kernel, grid, block, 0, stream,
                     nbr, emb, W, b, out);
}